// Round 2
// baseline (37329.257 us; speedup 1.0000x reference)
//
#include <hip/hip_runtime.h>

#define XD    64      // x_dim
#define HID   256     // hidden
#define G4    1024    // 4*hidden
#define TLEN  2048
#define BATCH 64

__device__ __forceinline__ float sigmf(float x) {
    return 1.0f / (1.0f + __expf(-x));
}
// tanh(x) = 1 - 2/(exp(2x)+1); __expf overflow/underflow saturates correctly (+/-1)
__device__ __forceinline__ float tanhfast(float x) {
    return 1.0f - 2.0f / (1.0f + __expf(2.0f * x));
}

// w_ih: (1024,64) row-major -> wihT: (64,1024); w_hh: (1024,256) -> whhT: (256,1024)
__global__ void transpose_weights(const float* __restrict__ wih,
                                  const float* __restrict__ whh,
                                  float* __restrict__ wihT,
                                  float* __restrict__ whhT) {
    int idx = blockIdx.x * blockDim.x + threadIdx.x;
    if (idx < G4 * XD) {
        int j = idx / XD, k = idx % XD;
        wihT[k * G4 + j] = wih[idx];
    }
    if (idx < G4 * HID) {
        int j = idx / HID, k = idx % HID;
        whhT[k * G4 + j] = whh[idx];
    }
}

// One block per batch element; 512 threads; thread t owns gate outputs 2t, 2t+1.
// Threads 0..255 additionally own cell state c[tid] in a register.
__global__ __launch_bounds__(512)
void lstm_seq(const float* __restrict__ x,      // (B, T, 64)
              const float* __restrict__ bias,   // (1024)
              const float* __restrict__ wihT,   // (64, 1024)
              const float* __restrict__ whhT,   // (256, 1024)
              float* __restrict__ out)          // (B, T, 256)
{
    __shared__ __align__(16) float xs[2][XD];   // double-buffered x_t
    __shared__ __align__(16) float hs[HID];     // h_{t-1}
    __shared__ __align__(16) float zs[G4];      // gate pre-activations

    const int b   = blockIdx.x;
    const int tid = threadIdx.x;

    const float2* __restrict__ wihT2 = (const float2*)wihT; // rows of 512 float2
    const float2* __restrict__ whhT2 = (const float2*)whhT;

    const float2 bj = ((const float2*)bias)[tid];

    const float* __restrict__ xb = x   + (size_t)b * TLEN * XD;
    float*       __restrict__ ob = out + (size_t)b * TLEN * HID;

    // init state
    if (tid < HID) hs[tid] = 0.0f;
    float c = 0.0f;
    // stage x_0 (16 threads x float4 = 64 floats)
    if (tid < XD / 4) ((float4*)xs[0])[tid] = ((const float4*)xb)[tid];
    __syncthreads();

    for (int t = 0; t < TLEN; ++t) {
        const float* __restrict__ xcur = xs[t & 1];
        float2 acc = bj;

        // x-projection: k = 0..63
        #pragma unroll 4
        for (int k = 0; k < XD; k += 4) {
            const float4 xv = *(const float4*)(xcur + k);
            const float2 w0 = wihT2[(k + 0) * 512 + tid];
            const float2 w1 = wihT2[(k + 1) * 512 + tid];
            const float2 w2 = wihT2[(k + 2) * 512 + tid];
            const float2 w3 = wihT2[(k + 3) * 512 + tid];
            acc.x = fmaf(xv.x, w0.x, acc.x); acc.y = fmaf(xv.x, w0.y, acc.y);
            acc.x = fmaf(xv.y, w1.x, acc.x); acc.y = fmaf(xv.y, w1.y, acc.y);
            acc.x = fmaf(xv.z, w2.x, acc.x); acc.y = fmaf(xv.z, w2.y, acc.y);
            acc.x = fmaf(xv.w, w3.x, acc.x); acc.y = fmaf(xv.w, w3.y, acc.y);
        }
        // h-projection: k = 0..255
        #pragma unroll 2
        for (int k = 0; k < HID; k += 4) {
            const float4 hv = *(const float4*)(hs + k);
            const float2 w0 = whhT2[(k + 0) * 512 + tid];
            const float2 w1 = whhT2[(k + 1) * 512 + tid];
            const float2 w2 = whhT2[(k + 2) * 512 + tid];
            const float2 w3 = whhT2[(k + 3) * 512 + tid];
            acc.x = fmaf(hv.x, w0.x, acc.x); acc.y = fmaf(hv.x, w0.y, acc.y);
            acc.x = fmaf(hv.y, w1.x, acc.x); acc.y = fmaf(hv.y, w1.y, acc.y);
            acc.x = fmaf(hv.z, w2.x, acc.x); acc.y = fmaf(hv.z, w2.y, acc.y);
            acc.x = fmaf(hv.w, w3.x, acc.x); acc.y = fmaf(hv.w, w3.y, acc.y);
        }

        zs[2 * tid]     = acc.x;
        zs[2 * tid + 1] = acc.y;

        // prefetch x_{t+1} into the other buffer (last wave, 16 lanes x float4)
        if (t + 1 < TLEN && tid >= 496) {
            ((float4*)xs[(t + 1) & 1])[tid - 496] =
                ((const float4*)(xb + (size_t)(t + 1) * XD))[tid - 496];
        }
        __syncthreads();

        if (tid < HID) {
            const float zi = zs[tid];
            const float zf = zs[tid + HID];
            const float zg = zs[tid + 2 * HID];
            const float zo = zs[tid + 3 * HID];
            const float ig = sigmf(zi);
            const float fg = sigmf(zf);
            const float gg = tanhfast(zg);
            const float og = sigmf(zo);
            c = fg * c + ig * gg;
            const float hn = og * tanhfast(c);
            hs[tid] = hn;
            ob[(size_t)t * HID + tid] = hn;
        }
        __syncthreads();
    }
}

extern "C" void kernel_launch(void* const* d_in, const int* in_sizes, int n_in,
                              void* d_out, int out_size, void* d_ws, size_t ws_size,
                              hipStream_t stream) {
    const float* x    = (const float*)d_in[0];
    const float* wih  = (const float*)d_in[1];
    const float* whh  = (const float*)d_in[2];
    const float* bias = (const float*)d_in[3];
    float* out = (float*)d_out;

    float* wihT = (float*)d_ws;          // 64*1024 floats
    float* whhT = wihT + XD * G4;        // 256*1024 floats (total 1.31 MB of ws)

    hipLaunchKernelGGL(transpose_weights, dim3((G4 * HID + 255) / 256), dim3(256),
                       0, stream, wih, whh, wihT, whhT);
    hipLaunchKernelGGL(lstm_seq, dim3(BATCH), dim3(512), 0, stream,
                       x, bias, wihT, whhT, out);
}

// Round 3
// 26746.207 us; speedup vs baseline: 1.3957x; 1.3957x over previous
//
#include <hip/hip_runtime.h>

#define XD    64      // x_dim
#define HID   256     // hidden
#define G4    1024    // 4*hidden
#define TLEN  2048
#define BATCH 64
#define NPART 8       // blocks per chain
#define UPB   32      // hidden units per part
#define CPB   128     // gate columns per part (4 gates x 32 units)
#define CTR_STRIDE 32 // ints between per-chain counters (avoid false sharing)

__device__ __forceinline__ float sigmf(float x) {
    return 1.0f / (1.0f + __expf(-x));
}
// tanh(x) = 1 - 2/(exp(2x)+1); __expf saturation gives correct +/-1 tails
__device__ __forceinline__ float tanhfast(float x) {
    return 1.0f - 2.0f / (1.0f + __expf(2.0f * x));
}

// Zero h_{-1} buffer (hbuf[1]) and the per-chain step counters.
// Runs every launch (ws is re-poisoned to 0xAA before each timed call).
__global__ void init_ws(float* __restrict__ hbuf1, int* __restrict__ ctr) {
    const int b = blockIdx.x, i = threadIdx.x;
    hbuf1[b * HID + i] = 0.0f;
    if (i == 0) ctr[b * CTR_STRIDE] = 0;
}

// 512 blocks = 64 chains x 8 parts, 256 threads, 2 blocks/CU (all co-resident).
// Part owns units [part*32, part*32+32). Thread t: col = t>>1 (0..127),
// half = t&1; holds rows [half*160, half*160+160) of combined [w_ih | w_hh]
// for global gate column j = (col>>5)*256 + part*32 + (col&31), in 40 float4 regs.
__global__ __launch_bounds__(256, 2)
void lstm_par(const float* __restrict__ x,     // (B, T, 64)
              const float* __restrict__ wih,   // (1024, 64) row-major
              const float* __restrict__ whh,   // (1024, 256) row-major
              const float* __restrict__ bias,  // (1024)
              float* __restrict__ out,         // (B, T, 256)
              float* __restrict__ hbuf,        // (2, B, 256) exchange buffer
              int* __restrict__ ctr)           // (B) strided counters
{
    const int b    = blockIdx.x >> 3;
    const int part = blockIdx.x & 7;
    const int tid  = threadIdx.x;
    const int col  = tid >> 1;
    const int half = tid & 1;
    const int q    = col >> 5;                 // gate index (i,f,g,o)
    const int u    = col & 31;                 // unit within part
    const int j    = q * 256 + part * UPB + u; // global gate column

    __shared__ __align__(16) float vec[XD + HID]; // [x_t | h_{t-1}]
    __shared__ float zsh[CPB];

    // ---- one-time: weights into registers (amortized over 2048 steps) ----
    float4 w4[40];
    {
        const float4* wihr = (const float4*)(wih + (size_t)j * XD);
        const float4* whhr = (const float4*)(whh + (size_t)j * HID);
        if (half == 0) {
            #pragma unroll
            for (int i = 0; i < 16; ++i) w4[i] = wihr[i];        // w_ih[j][0:64]
            #pragma unroll
            for (int i = 0; i < 24; ++i) w4[16 + i] = whhr[i];   // w_hh[j][0:96]
        } else {
            #pragma unroll
            for (int i = 0; i < 40; ++i) w4[i] = whhr[24 + i];   // w_hh[j][96:256]
        }
    }
    const float bj = (half == 0) ? bias[j] : 0.0f;

    int* ctrb = ctr + b * CTR_STRIDE;
    const float* __restrict__ xb = x + (size_t)b * TLEN * XD;
    float* __restrict__ ob = out + (size_t)b * TLEN * HID;

    float c = 0.0f; // thread tid<32 owns cell state of unit tid

    for (int t = 0; t < TLEN; ++t) {
        // ---- wait until all 8 parts published h_{t-1} (ctr >= 8t) ----
        if (tid == 0 && t > 0) {
            const int target = 8 * t;
            int guard = 0;
            while (__hip_atomic_load(ctrb, __ATOMIC_ACQUIRE,
                                     __HIP_MEMORY_SCOPE_AGENT) < target) {
                __builtin_amdgcn_s_sleep(2);
                if (++guard > 50000) break; // hang-guard: corrupt, don't deadlock
            }
        }
        __syncthreads(); // (A)

        // ---- stage x_t and h_{t-1} into LDS ----
        if (tid < XD) vec[tid] = xb[(size_t)t * XD + tid];
        {
            const float* hprev = hbuf + ((size_t)((t + 1) & 1) * BATCH + b) * HID;
            vec[XD + tid] = __hip_atomic_load(hprev + tid, __ATOMIC_RELAXED,
                                              __HIP_MEMORY_SCOPE_AGENT);
        }
        __syncthreads(); // (B)

        // ---- 160-FMA half-dot from register weights, LDS-broadcast operands ----
        float4 acc = make_float4(bj, 0.f, 0.f, 0.f);
        const float4* vb = ((const float4*)vec) + half * 40;
        #pragma unroll
        for (int i = 0; i < 40; ++i) {
            const float4 v = vb[i];
            acc.x = fmaf(w4[i].x, v.x, acc.x);
            acc.y = fmaf(w4[i].y, v.y, acc.y);
            acc.z = fmaf(w4[i].z, v.z, acc.z);
            acc.w = fmaf(w4[i].w, v.w, acc.w);
        }
        float z = (acc.x + acc.y) + (acc.z + acc.w);
        z += __shfl_xor(z, 1);            // combine the two halves of column j
        if (half == 0) zsh[col] = z;
        __syncthreads(); // (C)

        // ---- gates, state update, publish (threads 0..31; all in wave 0) ----
        if (tid < UPB) {
            const float zi = zsh[tid];
            const float zf = zsh[UPB + tid];
            const float zg = zsh[2 * UPB + tid];
            const float zo = zsh[3 * UPB + tid];
            const float ig = sigmf(zi);
            const float fg = sigmf(zf);
            const float gg = tanhfast(zg);
            const float og = sigmf(zo);
            c = fg * c + ig * gg;
            const float h = og * tanhfast(c);
            ob[(size_t)t * HID + part * UPB + tid] = h;
            float* hcur = hbuf + ((size_t)(t & 1) * BATCH + b) * HID;
            __hip_atomic_store(hcur + part * UPB + tid, h, __ATOMIC_RELAXED,
                               __HIP_MEMORY_SCOPE_AGENT);
        }
        // release-add: same wave as the h stores -> pre-fence vmcnt(0) covers them
        if (tid == 0) {
            __hip_atomic_fetch_add(ctrb, 1, __ATOMIC_RELEASE,
                                   __HIP_MEMORY_SCOPE_AGENT);
        }
    }
}

extern "C" void kernel_launch(void* const* d_in, const int* in_sizes, int n_in,
                              void* d_out, int out_size, void* d_ws, size_t ws_size,
                              hipStream_t stream) {
    const float* x    = (const float*)d_in[0];
    const float* wih  = (const float*)d_in[1];
    const float* whh  = (const float*)d_in[2];
    const float* bias = (const float*)d_in[3];
    float* out = (float*)d_out;

    float* hbuf = (float*)d_ws;                        // 2*64*256 floats = 128 KB
    int*   ctr  = (int*)((char*)d_ws + 2 * BATCH * HID * sizeof(float)); // 8 KB

    hipLaunchKernelGGL(init_ws, dim3(BATCH), dim3(HID), 0, stream,
                       hbuf + (size_t)BATCH * HID, ctr);
    hipLaunchKernelGGL(lstm_par, dim3(BATCH * NPART), dim3(256), 0, stream,
                       x, wih, whh, bias, out, hbuf, ctr);
}

// Round 4
// 13699.638 us; speedup vs baseline: 2.7248x; 1.9523x over previous
//
#include <hip/hip_runtime.h>

#define XD    64      // x_dim
#define HID   256     // hidden
#define G4    1024    // 4*hidden
#define TLEN  2048
#define BATCH 64
#define NPART 8       // blocks per chain
#define UPB   32      // hidden units per part
#define CPB   128     // gate columns per part (4 gates x 32 units)
#define FSTRIDE 16    // ints between chains' flag groups (64B line per chain)

__device__ __forceinline__ float sigmf(float x) {
    return 1.0f / (1.0f + __expf(-x));
}
// tanh(x) = 1 - 2/(exp(2x)+1); __expf saturation gives correct +/-1 tails
__device__ __forceinline__ float tanhfast(float x) {
    return 1.0f - 2.0f / (1.0f + __expf(2.0f * x));
}

// Zero h_{-1} buffer (hbuf[1]) and per-chain flag groups (ws is re-poisoned
// to 0xAA before every timed call, so this must run every launch).
__global__ void init_ws(float* __restrict__ hbuf1, int* __restrict__ flags) {
    const int b = blockIdx.x, i = threadIdx.x;
    hbuf1[b * HID + i] = 0.0f;
    if (i < FSTRIDE) flags[b * FSTRIDE + i] = 0;
}

// 512 blocks = 64 chains x 8 parts, 256 threads, 2 blocks/CU (all co-resident).
// Part owns units [part*32, part*32+32). Thread t: col = t>>1 (0..127),
// half = t&1; holds rows [half*160, half*160+160) of combined [w_ih | w_hh]
// for global gate column j = (col>>5)*256 + part*32 + (col&31), in 40 float4 regs.
// Sync protocol: part stores flag[b][part] = t+1 (release, agent) after
// publishing its h-slice; pollers spin on RELAXED agent loads (no per-poll
// cache invalidate) until all 8 flags >= t.
__global__ __launch_bounds__(256, 2)
void lstm_par(const float* __restrict__ x,     // (B, T, 64)
              const float* __restrict__ wih,   // (1024, 64) row-major
              const float* __restrict__ whh,   // (1024, 256) row-major
              const float* __restrict__ bias,  // (1024)
              float* __restrict__ out,         // (B, T, 256)
              float* __restrict__ hbuf,        // (2, B, 256) exchange buffer
              int* __restrict__ flags)         // (B, FSTRIDE) step stamps
{
    const int b    = blockIdx.x >> 3;
    const int part = blockIdx.x & 7;
    const int tid  = threadIdx.x;
    const int col  = tid >> 1;
    const int half = tid & 1;
    const int q    = col >> 5;                 // gate index (i,f,g,o)
    const int u    = col & 31;                 // unit within part
    const int j    = q * 256 + part * UPB + u; // global gate column

    __shared__ __align__(16) float vec[XD + HID]; // [x_t | h_{t-1}]
    __shared__ float zsh[CPB];

    // ---- one-time: weights into registers (amortized over 2048 steps) ----
    float4 w4[40];
    {
        const float4* wihr = (const float4*)(wih + (size_t)j * XD);
        const float4* whhr = (const float4*)(whh + (size_t)j * HID);
        if (half == 0) {
            #pragma unroll
            for (int i = 0; i < 16; ++i) w4[i] = wihr[i];        // w_ih[j][0:64]
            #pragma unroll
            for (int i = 0; i < 24; ++i) w4[16 + i] = whhr[i];   // w_hh[j][0:96]
        } else {
            #pragma unroll
            for (int i = 0; i < 40; ++i) w4[i] = whhr[24 + i];   // w_hh[j][96:256]
        }
    }
    const float bj = (half == 0) ? bias[j] : 0.0f;

    int* __restrict__ fb = flags + b * FSTRIDE;
    const float* __restrict__ xb = x + (size_t)b * TLEN * XD;
    float* __restrict__ ob = out + (size_t)b * TLEN * HID;

    float c = 0.0f;                       // thread tid<32 owns cell of unit tid
    float xreg = (tid < XD) ? xb[tid] : 0.0f;   // x_0 prefetch

    for (int t = 0; t < TLEN; ++t) {
        // ---- wave 0: wait until all 8 parts published h_{t-1} ----
        if (tid < 64 && t > 0) {
            const int lane = tid & 7;     // 64 lanes cover 8 flags (32B, 1 txn)
            int guard = 0;
            for (;;) {
                const int v = __hip_atomic_load(fb + lane, __ATOMIC_RELAXED,
                                                __HIP_MEMORY_SCOPE_AGENT);
                if (__all(v >= t)) break;
                __builtin_amdgcn_s_sleep(1);
                if (++guard > 100000) break; // hang-guard: corrupt, don't deadlock
            }
        }
        __syncthreads(); // (A)

        // ---- stage x_t (from prefetch reg) and h_{t-1} into LDS ----
        if (tid < XD) vec[tid] = xreg;
        {
            const float* hprev = hbuf + ((size_t)((t + 1) & 1) * BATCH + b) * HID;
            vec[XD + tid] = __hip_atomic_load(hprev + tid, __ATOMIC_RELAXED,
                                              __HIP_MEMORY_SCOPE_AGENT);
        }
        __syncthreads(); // (B)

        // prefetch next x (latency overlapped by compute + next spin)
        if (t + 1 < TLEN && tid < XD) xreg = xb[(size_t)(t + 1) * XD + tid];

        // ---- 160-FMA half-dot: register weights x LDS-broadcast operands ----
        float4 acc = make_float4(bj, 0.f, 0.f, 0.f);
        const float4* vb = ((const float4*)vec) + half * 40;
        #pragma unroll
        for (int i = 0; i < 40; ++i) {
            const float4 v = vb[i];
            acc.x = fmaf(w4[i].x, v.x, acc.x);
            acc.y = fmaf(w4[i].y, v.y, acc.y);
            acc.z = fmaf(w4[i].z, v.z, acc.z);
            acc.w = fmaf(w4[i].w, v.w, acc.w);
        }
        float z = (acc.x + acc.y) + (acc.z + acc.w);
        z += __shfl_xor(z, 1);            // combine the two halves of column j
        if (half == 0) zsh[col] = z;
        __syncthreads(); // (C)

        // ---- gates, state update, publish (threads 0..31; all in wave 0) ----
        float h;
        if (tid < UPB) {
            const float zi = zsh[tid];
            const float zf = zsh[UPB + tid];
            const float zg = zsh[2 * UPB + tid];
            const float zo = zsh[3 * UPB + tid];
            const float ig = sigmf(zi);
            const float fg = sigmf(zf);
            const float gg = tanhfast(zg);
            const float og = sigmf(zo);
            c = fg * c + ig * gg;
            h = og * tanhfast(c);
            float* hcur = hbuf + ((size_t)(t & 1) * BATCH + b) * HID;
            __hip_atomic_store(hcur + part * UPB + tid, h, __ATOMIC_RELAXED,
                               __HIP_MEMORY_SCOPE_AGENT);
        }
        // release stamp: same wave as the h stores -> its vmcnt(0) drain covers
        // them; h is in LLC before the flag is visible.
        if (tid == 0) {
            __hip_atomic_store(fb + part, t + 1, __ATOMIC_RELEASE,
                               __HIP_MEMORY_SCOPE_AGENT);
        }
        // output store AFTER the flag: off the inter-part critical path
        if (tid < UPB) {
            ob[(size_t)t * HID + part * UPB + tid] = h;
        }
    }
}

extern "C" void kernel_launch(void* const* d_in, const int* in_sizes, int n_in,
                              void* d_out, int out_size, void* d_ws, size_t ws_size,
                              hipStream_t stream) {
    const float* x    = (const float*)d_in[0];
    const float* wih  = (const float*)d_in[1];
    const float* whh  = (const float*)d_in[2];
    const float* bias = (const float*)d_in[3];
    float* out = (float*)d_out;

    float* hbuf  = (float*)d_ws;                       // 2*64*256 floats = 128 KB
    int*   flags = (int*)((char*)d_ws + 2 * BATCH * HID * sizeof(float)); // 4 KB

    hipLaunchKernelGGL(init_ws, dim3(BATCH), dim3(HID), 0, stream,
                       hbuf + (size_t)BATCH * HID, flags);
    hipLaunchKernelGGL(lstm_par, dim3(BATCH * NPART), dim3(256), 0, stream,
                       x, wih, whh, bias, out, hbuf, flags);
}